// Round 11
// baseline (329.436 us; speedup 1.0000x reference)
//
#include <hip/hip_runtime.h>
#include <hip/hip_bf16.h>

// SoftmaxAttention: B=64, Lc=Lr=512, D=768, fp32 in/out.
// 4 dispatches per chunk:
//   k_main : fused grid. role gemm: S = C R^T (fp16 2-term split MFMA, fp32 acc),
//            single-buffer LDS, 2-DEEP register prefetch (sets A/B, loads issued
//            right after the consuming convert -> ~2-iter in-flight window),
//            setprio(1) around MFMA cluster, writes S only.
//            role prep: X fp32 -> XT fp16 [d][n] (RT/CT).
//   k_sm1  : rows of S: row-softmax (rmask) -> Wc fp16 (normalized); + colmax partials.
//   k_sm2  : single pass: Wr = exp(S^T - M) fp16 UNNORMALIZED + invr[r] per-row scale.
//   k_pv   : out_c = Wc@R * cmask ; out_r = (Wr@C) * rmask * invr.
// Mask semantics: w_j = m_j exp(t_j - M) / (S_act + EPS*Z),
//   t = s*m, M = max_j t_j (=max(max_act,0) if any inactive),
//   Z = S_act + n_inact*exp(-M), EPS=1e-13.
// LDS fp16 tiles are [row][32 f16] (64B rows); 16B-granule XOR swizzle
//   slot(r,g) = g ^ ((r>>1)&3)  -> 2-way bank aliasing (free).

#define BATCH 64
#define LSEQ 512
#define DMODEL 768

typedef __attribute__((ext_vector_type(4))) float f32x4;
typedef __attribute__((ext_vector_type(8))) _Float16 f16x8;
typedef __attribute__((ext_vector_type(4))) unsigned short u16x4;
typedef __attribute__((ext_vector_type(8))) unsigned short u16x8;

__device__ __forceinline__ unsigned short h2u(_Float16 h) {
  union { _Float16 h; unsigned short u; } v; v.h = h; return v.u;
}
__device__ __forceinline__ void gload16(const void* g, void* l) {
  __builtin_amdgcn_global_load_lds(
      (const __attribute__((address_space(1))) unsigned int*)g,
      (__attribute__((address_space(3))) unsigned int*)l, 16, 0, 0);
}
__device__ __forceinline__ int swz(int row, int g) {
  return row * 64 + ((g ^ ((row >> 1) & 3)) << 4);
}
__device__ __forceinline__ f32x4 mfma16(f16x8 a, f16x8 b, f32x4 c) {
  return __builtin_amdgcn_mfma_f32_16x16x32_f16(a, b, c, 0, 0, 0);
}
// bijective XCD-chunked swizzle (m204 form)
__device__ __forceinline__ int xcd_swz(int fid, int nwg) {
  const int q = nwg >> 3, r = nwg & 7;
  const int x = fid & 7, idx = fid >> 3;
  return (x < r ? x * (q + 1) : r * (q + 1) + (x - r) * q) + idx;
}

// ---- fused gemm + prep.  1-D grid 208*nb (per 13 nids: 1 gemm + 12 prep) ----
__global__ __launch_bounds__(256) void k_main(
    const float* __restrict__ Cg, const float* __restrict__ Rg,
    float* __restrict__ S,
    unsigned short* __restrict__ RT, unsigned short* __restrict__ CT,
    int b0, int nb) {
  __shared__ __align__(16) char smem[24576];
  const int nid = xcd_swz(blockIdx.x, 208 * nb);
  const int role = nid % 13;
  const int tid = threadIdx.x;

  if (role != 0) {
    // ---------------- prep role ----------------
    const int pid = (nid / 13) * 12 + role - 1;
    const int bz = pid / 192;
    const int rem = pid % 192;
    const int n0 = (rem & 7) * 64;
    int y = rem >> 3;
    const float* X;
    unsigned short* XT;
    if (y < 12) { X = Rg; XT = RT; } else { y -= 12; X = Cg; XT = CT; }
    const int d0 = y * 64;
    float (*tile)[65] = (float(*)[65])smem;
    const int i = tid >> 2, s4 = (tid & 3) * 4;
    const float* Xb = X + ((size_t)(b0 + bz) * LSEQ + n0 + i) * DMODEL + d0;
#pragma unroll
    for (int kk = 0; kk < 4; ++kk) {
      const int j = kk * 16 + s4;
      const f32x4 v = *(const f32x4*)(Xb + j);
#pragma unroll
      for (int k = 0; k < 4; ++k) tile[i][j + k] = v[k];
    }
    __syncthreads();
    unsigned short* Ob = XT + ((size_t)bz * DMODEL + d0 + i) * LSEQ + n0;
#pragma unroll
    for (int kk = 0; kk < 4; ++kk) {
      const int n = kk * 16 + s4;
      u16x4 h;
#pragma unroll
      for (int k = 0; k < 4; ++k) h[k] = h2u((_Float16)tile[n + k][i]);
      *(u16x4*)(Ob + n) = h;
    }
    return;
  }

  // ---------------- gemm role (2-deep reg prefetch) ----------------
  char* AhiB = smem;
  char* AloB = smem + 8192;
  char* BhiB = smem + 16384;
  const int gidx = nid / 13;
  const int bz = gidx >> 4;
  const int c0 = (gidx & 3) * 128;
  const int r0 = ((gidx >> 2) & 3) * 128;
  const int lane = tid & 63;
  const int w = tid >> 6;
  const int wm = (w & 1) * 64, wr = (w >> 1) * 64;
  const int l15 = lane & 15, kg = lane >> 4;
  const int srow = tid >> 2, sg = tid & 3;
  const float* Ca = Cg + ((size_t)(b0 + bz) * LSEQ + c0 + srow) * DMODEL + sg * 8;
  const float* Ca2 = Ca + (size_t)64 * DMODEL;
  const float* Ra = Rg + ((size_t)(b0 + bz) * LSEQ + r0 + srow) * DMODEL + sg * 8;
  const float* Ra2 = Ra + (size_t)64 * DMODEL;
  const int wA0 = swz(srow, sg), wA1 = swz(srow + 64, sg);

#define GM_LOAD(S0a, S0b, S1a, S1b, T0a, T0b, T1a, T1b, kn)  \
  S0a = *(const f32x4*)(Ca + (kn));                          \
  S0b = *(const f32x4*)(Ca + (kn) + 4);                      \
  S1a = *(const f32x4*)(Ca2 + (kn));                         \
  S1b = *(const f32x4*)(Ca2 + (kn) + 4);                     \
  T0a = *(const f32x4*)(Ra + (kn));                          \
  T0b = *(const f32x4*)(Ra + (kn) + 4);                      \
  T1a = *(const f32x4*)(Ra2 + (kn));                         \
  T1b = *(const f32x4*)(Ra2 + (kn) + 4);

// One K-step: convert set -> reload set (2 steps ahead, WAR after convert)
// -> barrier -> LDS write -> barrier -> ds_read frags -> MFMA.
#define GM_PHASE(S0a, S0b, S1a, S1b, T0a, T0b, T1a, T1b, refill, kn)                         \
  do {                                                                                       \
    f16x8 h0, l0, h1, l1, bh0, bh1;                                                          \
    _Pragma("unroll") for (int k = 0; k < 4; ++k) {                                          \
      float x = S0a[k]; _Float16 h = (_Float16)x; h0[k] = h; l0[k] = (_Float16)(x - (float)h); \
      x = S0b[k]; h = (_Float16)x; h0[4 + k] = h; l0[4 + k] = (_Float16)(x - (float)h);        \
      x = S1a[k]; h = (_Float16)x; h1[k] = h; l1[k] = (_Float16)(x - (float)h);                \
      x = S1b[k]; h = (_Float16)x; h1[4 + k] = h; l1[4 + k] = (_Float16)(x - (float)h);        \
      bh0[k] = (_Float16)T0a[k]; bh0[4 + k] = (_Float16)T0b[k];                                \
      bh1[k] = (_Float16)T1a[k]; bh1[4 + k] = (_Float16)T1b[k];                                \
    }                                                                                        \
    if (refill) { GM_LOAD(S0a, S0b, S1a, S1b, T0a, T0b, T1a, T1b, kn) }                      \
    __syncthreads(); /* prev iter's frag reads done */                                       \
    *(f16x8*)(AhiB + wA0) = h0;                                                              \
    *(f16x8*)(AloB + wA0) = l0;                                                              \
    *(f16x8*)(AhiB + wA1) = h1;                                                              \
    *(f16x8*)(AloB + wA1) = l1;                                                              \
    *(f16x8*)(BhiB + wA0) = bh0;                                                             \
    *(f16x8*)(BhiB + wA1) = bh1;                                                             \
    __syncthreads();                                                                         \
    f16x8 ah[4], al[4], bh[4];                                                               \
    _Pragma("unroll") for (int f = 0; f < 4; ++f) {                                          \
      ah[f] = *(const f16x8*)(AhiB + swz(wm + f * 16 + l15, kg));                            \
      al[f] = *(const f16x8*)(AloB + swz(wm + f * 16 + l15, kg));                            \
      bh[f] = *(const f16x8*)(BhiB + swz(wr + f * 16 + l15, kg));                            \
    }                                                                                        \
    __builtin_amdgcn_s_setprio(1);                                                           \
    _Pragma("unroll") for (int fm = 0; fm < 4; ++fm)                                         \
      _Pragma("unroll") for (int fr = 0; fr < 4; ++fr) {                                     \
        acc[fm][fr] = mfma16(ah[fm], bh[fr], acc[fm][fr]);                                   \
        acc[fm][fr] = mfma16(al[fm], bh[fr], acc[fm][fr]);                                   \
      }                                                                                      \
    __builtin_amdgcn_s_setprio(0);                                                           \
  } while (0)

  f32x4 pA0a, pA0b, pA1a, pA1b, pB0a, pB0b, pB1a, pB1b;  // set A (even steps)
  f32x4 qA0a, qA0b, qA1a, qA1b, qB0a, qB0b, qB1a, qB1b;  // set B (odd steps)
  GM_LOAD(pA0a, pA0b, pA1a, pA1b, pB0a, pB0b, pB1a, pB1b, 0)
  GM_LOAD(qA0a, qA0b, qA1a, qA1b, qB0a, qB0b, qB1a, qB1b, 32)
  f32x4 acc[4][4] = {};
#pragma unroll 2
  for (int t = 0; t < 24; t += 2) {
    GM_PHASE(pA0a, pA0b, pA1a, pA1b, pB0a, pB0b, pB1a, pB1b,
             (t + 2 < 24), (t + 2) * 32);
    GM_PHASE(qA0a, qA0b, qA1a, qA1b, qB0a, qB0b, qB1a, qB1b,
             (t + 3 < 24), (t + 3) * 32);
  }
#undef GM_PHASE
#undef GM_LOAD
  const int g4 = (lane >> 4) * 4;
  float* Sb = S + ((size_t)bz * LSEQ + c0) * LSEQ + r0;
#pragma unroll
  for (int fm = 0; fm < 4; ++fm)
#pragma unroll
    for (int fr = 0; fr < 4; ++fr)
#pragma unroll
      for (int reg = 0; reg < 4; ++reg)
        Sb[(size_t)(wm + fm * 16 + g4 + reg) * LSEQ + wr + fr * 16 + l15] = acc[fm][fr][reg];
}

// ---- sm1: rows of S (c-major). row-softmax over r (rmask) -> Wc fp16.
// Also: per-stripe column max over active c (cmask) -> colpart[bz][blk][512].
// grid (8 c-tiles, nb)
__global__ __launch_bounds__(256) void k_sm1(
    const float* __restrict__ Sg, const int* __restrict__ rmask,
    const int* __restrict__ cmask, unsigned short* __restrict__ WcG,
    float* __restrict__ colpart, int b0) {
  __shared__ float maskRf[LSEQ];
  __shared__ float cmf[64];
  __shared__ float cmLDS[4][LSEQ];
  __shared__ float s_ninact;
  const int bz = blockIdx.y;
  const int b = b0 + bz;
  const int c0 = blockIdx.x * 64;
  const int tid = threadIdx.x;
  const int lane = tid & 63;
  const int w = tid >> 6;
  if (tid == 0) s_ninact = 0.f;
  __syncthreads();
  float cnt = 0.f;
  for (int j = tid; j < LSEQ; j += 256) {
    const float m = (float)rmask[(size_t)b * LSEQ + j];
    maskRf[j] = m;
    cnt += 1.f - m;
  }
  if (tid < 64) cmf[tid] = (float)cmask[(size_t)b * LSEQ + c0 + tid];
#pragma unroll
  for (int s = 1; s < 64; s <<= 1) cnt += __shfl_xor(cnt, s);
  if (lane == 0) atomicAdd(&s_ninact, cnt);
  __syncthreads();
  const float ninact = s_ninact;
  float mk[8];
#pragma unroll
  for (int k = 0; k < 8; ++k) mk[k] = maskRf[lane * 8 + k];
  float cmax[8];
#pragma unroll
  for (int k = 0; k < 8; ++k) cmax[k] = -1e30f;

  for (int rr = 0; rr < 16; ++rr) {
    const int c = c0 + w * 16 + rr;
    const float* Lr = Sg + ((size_t)bz * LSEQ + c) * LSEQ + lane * 8;
    const f32x4 v0 = *(const f32x4*)(Lr);
    const f32x4 v1 = *(const f32x4*)(Lr + 4);
    float v[8];
#pragma unroll
    for (int k = 0; k < 4; ++k) { v[k] = v0[k]; v[k + 4] = v1[k]; }
    if (cmf[w * 16 + rr] > 0.5f) {
#pragma unroll
      for (int k = 0; k < 8; ++k) cmax[k] = fmaxf(cmax[k], v[k]);
    }
    float mx = -1e30f;
#pragma unroll
    for (int k = 0; k < 8; ++k)
      if (mk[k] > 0.5f) mx = fmaxf(mx, v[k]);
#pragma unroll
    for (int s = 1; s < 64; s <<= 1) mx = fmaxf(mx, __shfl_xor(mx, s));
    const float M = (ninact > 0.5f) ? fmaxf(mx, 0.f) : mx;
    float p[8];
    float sum = 0.f;
#pragma unroll
    for (int k = 0; k < 8; ++k) {
      p[k] = mk[k] * __expf(fminf(v[k] - M, 0.f));
      sum += p[k];
    }
#pragma unroll
    for (int s = 1; s < 64; s <<= 1) sum += __shfl_xor(sum, s);
    const float Z = sum + ((ninact > 0.5f) ? ninact * __expf(-M) : 0.f);
    const float inv = 1.f / (sum + 1e-13f * Z);
    u16x8 h;
#pragma unroll
    for (int k = 0; k < 8; ++k) h[k] = h2u((_Float16)(p[k] * inv));
    *(u16x8*)(WcG + ((size_t)bz * LSEQ + c) * LSEQ + lane * 8) = h;
  }
#pragma unroll
  for (int k = 0; k < 8; ++k) cmLDS[w][lane * 8 + k] = cmax[k];
  __syncthreads();
  float* cp = colpart + ((size_t)bz * 8 + blockIdx.x) * LSEQ;
  for (int r = tid; r < LSEQ; r += 256) {
    const float pm = fmaxf(fmaxf(cmLDS[0][r], cmLDS[1][r]),
                           fmaxf(cmLDS[2][r], cmLDS[3][r]));
    cp[r] = pm;
  }
}

// ---- sm2: SINGLE pass. Wr[r][c] = cmask[c]*exp(S[c][r]-M[r]) fp16 (unnormalized),
// per-row inv -> invr[r]. Final M known up-front from colpart. grid (8 r-tiles, nb)
__global__ __launch_bounds__(256) void k_sm2(
    const float* __restrict__ Sg, const int* __restrict__ cmask,
    const float* __restrict__ colpart, unsigned short* __restrict__ WrG,
    float* __restrict__ invrG, int b0) {
  __shared__ float maskCf[LSEQ];
  __shared__ float lt[64 * 65];
  __shared__ float Ms[64];
  __shared__ float s_ninact;
  const int bz = blockIdx.y;
  const int b = b0 + bz;
  const int r0 = blockIdx.x * 64;
  const int tid = threadIdx.x;
  const int lane = tid & 63;
  if (tid == 0) s_ninact = 0.f;
  __syncthreads();
  float cnt = 0.f;
  for (int j = tid; j < LSEQ; j += 256) {
    const float m = (float)cmask[(size_t)b * LSEQ + j];
    maskCf[j] = m;
    cnt += 1.f - m;
  }
#pragma unroll
  for (int s = 1; s < 64; s <<= 1) cnt += __shfl_xor(cnt, s);
  if (lane == 0) atomicAdd(&s_ninact, cnt);
  __syncthreads();
  const float ninact = s_ninact;
  if (tid < 64) {
    const float* cp = colpart + (size_t)bz * 8 * LSEQ + r0 + tid;
    float m = cp[0];
#pragma unroll
    for (int blk = 1; blk < 8; ++blk) m = fmaxf(m, cp[(size_t)blk * LSEQ]);
    Ms[tid] = (ninact > 0.5f) ? fmaxf(m, 0.f) : m;
  }
  __syncthreads();
  const float* Sb = Sg + (size_t)bz * LSEQ * LSEQ;
  const int sti = tid >> 2, stj = (tid & 3) * 16;  // staging role
  const int rl = tid >> 2, cs = tid & 3;           // compute role (same split)
  const float M = Ms[rl];
  float psum = 0.f;
  for (int ct = 0; ct < 8; ++ct) {
    __syncthreads();  // prev tile reads done
    const float* src = Sb + (size_t)(ct * 64 + sti) * LSEQ + r0 + stj;
#pragma unroll
    for (int q = 0; q < 4; ++q)
      *(f32x4*)&lt[sti * 65 + stj + q * 4] = *(const f32x4*)(src + q * 4);
    __syncthreads();
    const int cb = ct * 64 + cs * 16;
    u16x8 h0, h1;
#pragma unroll
    for (int q = 0; q < 16; ++q) {
      const float v = lt[(cs * 16 + q) * 65 + rl];
      const float p = maskCf[cb + q] * __expf(fminf(v - M, 0.f));
      psum += p;
      if (q < 8) h0[q] = h2u((_Float16)p);
      else h1[q - 8] = h2u((_Float16)p);
    }
    unsigned short* dst = WrG + ((size_t)bz * LSEQ + r0 + rl) * LSEQ + cb;
    *(u16x8*)dst = h0;
    *(u16x8*)(dst + 8) = h1;
  }
  psum += __shfl_xor(psum, 1);
  psum += __shfl_xor(psum, 2);
  if (cs == 0) {
    const float Z = psum + ((ninact > 0.5f) ? ninact * __expf(-M) : 0.f);
    invrG[(size_t)bz * LSEQ + r0 + rl] = 1.f / (psum + 1e-13f * Z);
  }
}

// ---- PV: out[b][m][d] = (sum_n W[m,n]*Vt[d,n]) * scaleM[m], fp16 MFMA ----
// job0: scaleM = cmask; job1: scaleM = rmask * invr (Wr is unnormalized).
// 1-D grid 48*nb, XCD-chunked; 128x128 tile, BK=32, double-buffered LDS.
__global__ __launch_bounds__(256) void k_pv(
    const unsigned short* __restrict__ WcG, const unsigned short* __restrict__ WrG,
    const unsigned short* __restrict__ RT, const unsigned short* __restrict__ CT,
    const int* __restrict__ cmask, const int* __restrict__ rmask,
    const float* __restrict__ invrG, float* __restrict__ out, int b0, int nb) {
  __shared__ __align__(16) unsigned short Alds[2][128 * 32];
  __shared__ __align__(16) unsigned short Blds[2][128 * 32];
  __shared__ float maskMf[128];
  const int nid = xcd_swz(blockIdx.x, 48 * nb);
  const int bz = nid / 48;
  const int rem = nid % 48;
  const int m0 = (rem & 3) * 128;
  int y = rem >> 2;
  const int job = (y >= 6) ? 1 : 0;
  if (job) y -= 6;
  const unsigned short* Wg = job ? WrG : WcG;
  const unsigned short* Vt = job ? CT : RT;
  const int* maskM = job ? rmask : cmask;
  float* outp = out + (job ? (size_t)BATCH * LSEQ * DMODEL : 0);
  const int d0 = y * 128;
  const int tid = threadIdx.x;
  const int lane = tid & 63;
  const int w = tid >> 6;
  const int wm = (w & 1) * 64, wd = (w >> 1) * 64;
  const int l15 = lane & 15, kg = lane >> 4;
  if (tid < 128) {
    float m = (float)maskM[(size_t)(b0 + bz) * LSEQ + m0 + tid];
    if (job) m *= invrG[(size_t)bz * LSEQ + m0 + tid];
    maskMf[tid] = m;
  }
  const unsigned short* Wb = Wg + ((size_t)bz * LSEQ + m0) * LSEQ;
  const unsigned short* Vb = Vt + ((size_t)bz * DMODEL + d0) * LSEQ;
  const int sr = tid >> 2, gp = tid & 3;
  const int gs0 = (gp ^ ((sr >> 1) & 3)) * 8;
  const int gs1 = (gp ^ (((sr + 64) >> 1) & 3)) * 8;

#define PV_STAGE(buf, k0)                                             \
  do {                                                                \
    gload16(Wb + (size_t)sr * LSEQ + (k0) + gs0, &Alds[buf][tid * 8]);\
    gload16(Vb + (size_t)sr * LSEQ + (k0) + gs0, &Blds[buf][tid * 8]);\
    gload16(Wb + (size_t)(sr + 64) * LSEQ + (k0) + gs1,               \
            &Alds[buf][(256 + tid) * 8]);                             \
    gload16(Vb + (size_t)(sr + 64) * LSEQ + (k0) + gs1,               \
            &Blds[buf][(256 + tid) * 8]);                             \
  } while (0)

  f32x4 acc[4][4] = {};
  PV_STAGE(0, 0);
  __syncthreads();
  int cur = 0;
  for (int t = 0; t < 16; ++t) {
    if (t < 15) PV_STAGE(cur ^ 1, (t + 1) * 32);
    f16x8 a[4], bb[4];
#pragma unroll
    for (int f = 0; f < 4; ++f) {
      a[f] = *(const f16x8*)((const char*)Alds[cur] + swz(wm + f * 16 + l15, kg));
      bb[f] = *(const f16x8*)((const char*)Blds[cur] + swz(wd + f * 16 + l15, kg));
    }
#pragma unroll
    for (int fm = 0; fm < 4; ++fm)
#pragma unroll
      for (int fd = 0; fd < 4; ++fd)
        acc[fm][fd] = mfma16(a[fm], bb[fd], acc[fm][fd]);
    __syncthreads();
    cur ^= 1;
  }
#undef PV_STAGE
  const int g4 = (lane >> 4) * 4;
#pragma unroll
  for (int fm = 0; fm < 4; ++fm)
#pragma unroll
    for (int fd = 0; fd < 4; ++fd)
#pragma unroll
      for (int reg = 0; reg < 4; ++reg) {
        const int row = wm + fm * 16 + g4 + reg;
        const int col = wd + fd * 16 + l15;
        outp[((size_t)(b0 + bz) * LSEQ + m0 + row) * DMODEL + d0 + col] =
            acc[fm][fd][reg] * maskMf[row];
      }
}

extern "C" void kernel_launch(void* const* d_in, const int* in_sizes, int n_in,
                              void* d_out, int out_size, void* d_ws, size_t ws_size,
                              hipStream_t stream) {
  const float* context = (const float*)d_in[0];
  const float* response = (const float*)d_in[1];
  const int* cmask = (const int*)d_in[2];
  const int* rmask = (const int*)d_in[3];
  float* out = (float*)d_out;

  const size_t szS1 = (size_t)LSEQ * LSEQ * 4;
  const size_t szT1 = (size_t)LSEQ * DMODEL * 2;
  const size_t szW1 = (size_t)LSEQ * LSEQ * 2;
  const size_t szP1 = (size_t)8 * LSEQ * 4;
  const size_t szI1 = (size_t)LSEQ * 4;
  const size_t perBatch = szS1 + 2 * szT1 + 2 * szW1 + szP1 + szI1;
  int nbc = (int)(ws_size / perBatch);
  if (nbc > BATCH) nbc = BATCH;
  if (nbc < 1) nbc = 1;

  char* base = (char*)d_ws;
  const size_t szS = (size_t)nbc * szS1;
  const size_t szT = (size_t)nbc * szT1;
  const size_t szW = (size_t)nbc * szW1;
  const size_t szP = (size_t)nbc * szP1;
  float* S = (float*)base;
  unsigned short* RT = (unsigned short*)(base + szS);
  unsigned short* CT = (unsigned short*)(base + szS + szT);
  unsigned short* Wc = (unsigned short*)(base + szS + 2 * szT);
  unsigned short* Wr = (unsigned short*)(base + szS + 2 * szT + szW);
  float* colpart = (float*)(base + szS + 2 * szT + 2 * szW);
  float* invr = (float*)(base + szS + 2 * szT + 2 * szW + szP);

  for (int b0 = 0; b0 < BATCH; b0 += nbc) {
    int nb = BATCH - b0;
    if (nb > nbc) nb = nbc;
    dim3 blk(256);
    k_main<<<dim3(208 * nb), blk, 0, stream>>>(context, response, S, RT, CT, b0, nb);
    k_sm1<<<dim3(8, nb), blk, 0, stream>>>(S, rmask, cmask, Wc, colpart, b0);
    k_sm2<<<dim3(8, nb), blk, 0, stream>>>(S, cmask, colpart, Wr, invr, b0);
    k_pv<<<dim3(48 * nb), blk, 0, stream>>>(Wc, Wr, RT, CT, cmask, rmask, invr, out, b0, nb);
  }
}

// Round 12
// 270.008 us; speedup vs baseline: 1.2201x; 1.2201x over previous
//
#include <hip/hip_runtime.h>
#include <hip/hip_bf16.h>

// SoftmaxAttention: B=64, Lc=Lr=512, D=768, fp32 in/out.
// 4 dispatches per chunk:
//   k_main : fused grid. role gemm: S = fp16(C) * fp16(R)^T (plain fp16 MFMA,
//            fp32 acc; B-side fp16 rounding error was already present — 1-term
//            adds only sqrt(2) on logit error, absmax stays well under threshold).
//            Single 16.3 KB LDS buffer, 1-deep reg prefetch, setprio around MFMA.
//            role prep: X fp32 -> XT fp16 [d][n] (RT/CT).
//   k_sm1  : rows of S: row-softmax (rmask) -> Wc fp16 (normalized); + colmax partials.
//   k_sm2  : single pass: Wr = exp(S^T - M) fp16 UNNORMALIZED + invr[r] per-row scale.
//   k_pv   : out_c = Wc@R * cmask ; out_r = (Wr@C) * rmask * invr.
// Mask semantics: w_j = m_j exp(t_j - M) / (S_act + EPS*Z),
//   t = s*m, M = max_j t_j (=max(max_act,0) if any inactive),
//   Z = S_act + n_inact*exp(-M), EPS=1e-13.
// LDS fp16 tiles are [row][32 f16] (64B rows); 16B-granule XOR swizzle
//   slot(r,g) = g ^ ((r>>1)&3)  -> 2-way bank aliasing (free).

#define BATCH 64
#define LSEQ 512
#define DMODEL 768

typedef __attribute__((ext_vector_type(4))) float f32x4;
typedef __attribute__((ext_vector_type(8))) _Float16 f16x8;
typedef __attribute__((ext_vector_type(4))) unsigned short u16x4;
typedef __attribute__((ext_vector_type(8))) unsigned short u16x8;

__device__ __forceinline__ unsigned short h2u(_Float16 h) {
  union { _Float16 h; unsigned short u; } v; v.h = h; return v.u;
}
__device__ __forceinline__ void gload16(const void* g, void* l) {
  __builtin_amdgcn_global_load_lds(
      (const __attribute__((address_space(1))) unsigned int*)g,
      (__attribute__((address_space(3))) unsigned int*)l, 16, 0, 0);
}
__device__ __forceinline__ int swz(int row, int g) {
  return row * 64 + ((g ^ ((row >> 1) & 3)) << 4);
}
__device__ __forceinline__ f32x4 mfma16(f16x8 a, f16x8 b, f32x4 c) {
  return __builtin_amdgcn_mfma_f32_16x16x32_f16(a, b, c, 0, 0, 0);
}
// bijective XCD-chunked swizzle (m204 form)
__device__ __forceinline__ int xcd_swz(int fid, int nwg) {
  const int q = nwg >> 3, r = nwg & 7;
  const int x = fid & 7, idx = fid >> 3;
  return (x < r ? x * (q + 1) : r * (q + 1) + (x - r) * q) + idx;
}

// ---- fused gemm + prep.  1-D grid 208*nb (per 13 nids: 1 gemm + 12 prep) ----
__global__ __launch_bounds__(256) void k_main(
    const float* __restrict__ Cg, const float* __restrict__ Rg,
    float* __restrict__ S,
    unsigned short* __restrict__ RT, unsigned short* __restrict__ CT,
    int b0, int nb) {
  __shared__ __align__(16) char smem[16640];  // prep: [64][65] f32; gemm: A+B f16
  const int nid = xcd_swz(blockIdx.x, 208 * nb);
  const int role = nid % 13;
  const int tid = threadIdx.x;

  if (role != 0) {
    // ---------------- prep role ----------------
    const int pid = (nid / 13) * 12 + role - 1;
    const int bz = pid / 192;
    const int rem = pid % 192;
    const int n0 = (rem & 7) * 64;
    int y = rem >> 3;
    const float* X;
    unsigned short* XT;
    if (y < 12) { X = Rg; XT = RT; } else { y -= 12; X = Cg; XT = CT; }
    const int d0 = y * 64;
    float (*tile)[65] = (float(*)[65])smem;
    const int i = tid >> 2, s4 = (tid & 3) * 4;
    const float* Xb = X + ((size_t)(b0 + bz) * LSEQ + n0 + i) * DMODEL + d0;
#pragma unroll
    for (int kk = 0; kk < 4; ++kk) {
      const int j = kk * 16 + s4;
      const f32x4 v = *(const f32x4*)(Xb + j);
#pragma unroll
      for (int k = 0; k < 4; ++k) tile[i][j + k] = v[k];
    }
    __syncthreads();
    unsigned short* Ob = XT + ((size_t)bz * DMODEL + d0 + i) * LSEQ + n0;
#pragma unroll
    for (int kk = 0; kk < 4; ++kk) {
      const int n = kk * 16 + s4;
      u16x4 h;
#pragma unroll
      for (int k = 0; k < 4; ++k) h[k] = h2u((_Float16)tile[n + k][i]);
      *(u16x4*)(Ob + n) = h;
    }
    return;
  }

  // ---------------- gemm role (plain fp16, 1-deep reg prefetch) ----------------
  char* AhB = smem;           // 8 KB: A tile [128][32] f16 swizzled
  char* BhB = smem + 8192;    // 8 KB: B tile
  const int gidx = nid / 13;
  const int bz = gidx >> 4;
  const int c0 = (gidx & 3) * 128;
  const int r0 = ((gidx >> 2) & 3) * 128;
  const int lane = tid & 63;
  const int w = tid >> 6;
  const int wm = (w & 1) * 64, wr = (w >> 1) * 64;
  const int l15 = lane & 15, kg = lane >> 4;
  const int srow = tid >> 2, sg = tid & 3;
  const float* Ca = Cg + ((size_t)(b0 + bz) * LSEQ + c0 + srow) * DMODEL + sg * 8;
  const float* Ca2 = Ca + (size_t)64 * DMODEL;
  const float* Ra = Rg + ((size_t)(b0 + bz) * LSEQ + r0 + srow) * DMODEL + sg * 8;
  const float* Ra2 = Ra + (size_t)64 * DMODEL;
  const int wA0 = swz(srow, sg), wA1 = swz(srow + 64, sg);
  f32x4 a0a = *(const f32x4*)(Ca);
  f32x4 a0b = *(const f32x4*)(Ca + 4);
  f32x4 a1a = *(const f32x4*)(Ca2);
  f32x4 a1b = *(const f32x4*)(Ca2 + 4);
  f32x4 b0a = *(const f32x4*)(Ra);
  f32x4 b0b = *(const f32x4*)(Ra + 4);
  f32x4 b1a = *(const f32x4*)(Ra2);
  f32x4 b1b = *(const f32x4*)(Ra2 + 4);
  f32x4 acc[4][4] = {};
  for (int k0 = 0; k0 < DMODEL; k0 += 32) {
    f16x8 ha0, ha1, hb0, hb1;
#pragma unroll
    for (int k = 0; k < 4; ++k) {
      ha0[k] = (_Float16)a0a[k]; ha0[4 + k] = (_Float16)a0b[k];
      ha1[k] = (_Float16)a1a[k]; ha1[4 + k] = (_Float16)a1b[k];
      hb0[k] = (_Float16)b0a[k]; hb0[4 + k] = (_Float16)b0b[k];
      hb1[k] = (_Float16)b1a[k]; hb1[4 + k] = (_Float16)b1b[k];
    }
    __syncthreads();  // prev iter's frag reads done
    *(f16x8*)(AhB + wA0) = ha0;
    *(f16x8*)(AhB + wA1) = ha1;
    *(f16x8*)(BhB + wA0) = hb0;
    *(f16x8*)(BhB + wA1) = hb1;
    __syncthreads();
    if (k0 + 32 < DMODEL) {  // next K-step loads fly under ds_read + MFMA
      const int kn = k0 + 32;
      a0a = *(const f32x4*)(Ca + kn);
      a0b = *(const f32x4*)(Ca + kn + 4);
      a1a = *(const f32x4*)(Ca2 + kn);
      a1b = *(const f32x4*)(Ca2 + kn + 4);
      b0a = *(const f32x4*)(Ra + kn);
      b0b = *(const f32x4*)(Ra + kn + 4);
      b1a = *(const f32x4*)(Ra2 + kn);
      b1b = *(const f32x4*)(Ra2 + kn + 4);
    }
    f16x8 ah[4], bh[4];
#pragma unroll
    for (int f = 0; f < 4; ++f) {
      ah[f] = *(const f16x8*)(AhB + swz(wm + f * 16 + l15, kg));
      bh[f] = *(const f16x8*)(BhB + swz(wr + f * 16 + l15, kg));
    }
    __builtin_amdgcn_s_setprio(1);  // prefer MFMA waves over co-resident prep waves
#pragma unroll
    for (int fm = 0; fm < 4; ++fm)
#pragma unroll
      for (int fr = 0; fr < 4; ++fr)
        acc[fm][fr] = mfma16(ah[fm], bh[fr], acc[fm][fr]);
    __builtin_amdgcn_s_setprio(0);
  }
  const int g4 = (lane >> 4) * 4;
  float* Sb = S + ((size_t)bz * LSEQ + c0) * LSEQ + r0;
#pragma unroll
  for (int fm = 0; fm < 4; ++fm)
#pragma unroll
    for (int fr = 0; fr < 4; ++fr)
#pragma unroll
      for (int reg = 0; reg < 4; ++reg)
        Sb[(size_t)(wm + fm * 16 + g4 + reg) * LSEQ + wr + fr * 16 + l15] = acc[fm][fr][reg];
}

// ---- sm1: rows of S (c-major). row-softmax over r (rmask) -> Wc fp16.
// Also: per-stripe column max over active c (cmask) -> colpart[bz][blk][512].
// grid (8 c-tiles, nb)
__global__ __launch_bounds__(256) void k_sm1(
    const float* __restrict__ Sg, const int* __restrict__ rmask,
    const int* __restrict__ cmask, unsigned short* __restrict__ WcG,
    float* __restrict__ colpart, int b0) {
  __shared__ float maskRf[LSEQ];
  __shared__ float cmf[64];
  __shared__ float cmLDS[4][LSEQ];
  __shared__ float s_ninact;
  const int bz = blockIdx.y;
  const int b = b0 + bz;
  const int c0 = blockIdx.x * 64;
  const int tid = threadIdx.x;
  const int lane = tid & 63;
  const int w = tid >> 6;
  if (tid == 0) s_ninact = 0.f;
  __syncthreads();
  float cnt = 0.f;
  for (int j = tid; j < LSEQ; j += 256) {
    const float m = (float)rmask[(size_t)b * LSEQ + j];
    maskRf[j] = m;
    cnt += 1.f - m;
  }
  if (tid < 64) cmf[tid] = (float)cmask[(size_t)b * LSEQ + c0 + tid];
#pragma unroll
  for (int s = 1; s < 64; s <<= 1) cnt += __shfl_xor(cnt, s);
  if (lane == 0) atomicAdd(&s_ninact, cnt);
  __syncthreads();
  const float ninact = s_ninact;
  float mk[8];
#pragma unroll
  for (int k = 0; k < 8; ++k) mk[k] = maskRf[lane * 8 + k];
  float cmax[8];
#pragma unroll
  for (int k = 0; k < 8; ++k) cmax[k] = -1e30f;

  for (int rr = 0; rr < 16; ++rr) {
    const int c = c0 + w * 16 + rr;
    const float* Lr = Sg + ((size_t)bz * LSEQ + c) * LSEQ + lane * 8;
    const f32x4 v0 = *(const f32x4*)(Lr);
    const f32x4 v1 = *(const f32x4*)(Lr + 4);
    float v[8];
#pragma unroll
    for (int k = 0; k < 4; ++k) { v[k] = v0[k]; v[k + 4] = v1[k]; }
    if (cmf[w * 16 + rr] > 0.5f) {
#pragma unroll
      for (int k = 0; k < 8; ++k) cmax[k] = fmaxf(cmax[k], v[k]);
    }
    float mx = -1e30f;
#pragma unroll
    for (int k = 0; k < 8; ++k)
      if (mk[k] > 0.5f) mx = fmaxf(mx, v[k]);
#pragma unroll
    for (int s = 1; s < 64; s <<= 1) mx = fmaxf(mx, __shfl_xor(mx, s));
    const float M = (ninact > 0.5f) ? fmaxf(mx, 0.f) : mx;
    float p[8];
    float sum = 0.f;
#pragma unroll
    for (int k = 0; k < 8; ++k) {
      p[k] = mk[k] * __expf(fminf(v[k] - M, 0.f));
      sum += p[k];
    }
#pragma unroll
    for (int s = 1; s < 64; s <<= 1) sum += __shfl_xor(sum, s);
    const float Z = sum + ((ninact > 0.5f) ? ninact * __expf(-M) : 0.f);
    const float inv = 1.f / (sum + 1e-13f * Z);
    u16x8 h;
#pragma unroll
    for (int k = 0; k < 8; ++k) h[k] = h2u((_Float16)(p[k] * inv));
    *(u16x8*)(WcG + ((size_t)bz * LSEQ + c) * LSEQ + lane * 8) = h;
  }
#pragma unroll
  for (int k = 0; k < 8; ++k) cmLDS[w][lane * 8 + k] = cmax[k];
  __syncthreads();
  float* cp = colpart + ((size_t)bz * 8 + blockIdx.x) * LSEQ;
  for (int r = tid; r < LSEQ; r += 256) {
    const float pm = fmaxf(fmaxf(cmLDS[0][r], cmLDS[1][r]),
                           fmaxf(cmLDS[2][r], cmLDS[3][r]));
    cp[r] = pm;
  }
}

// ---- sm2: SINGLE pass. Wr[r][c] = cmask[c]*exp(S[c][r]-M[r]) fp16 (unnormalized),
// per-row inv -> invr[r]. Final M known up-front from colpart. grid (8 r-tiles, nb)
__global__ __launch_bounds__(256) void k_sm2(
    const float* __restrict__ Sg, const int* __restrict__ cmask,
    const float* __restrict__ colpart, unsigned short* __restrict__ WrG,
    float* __restrict__ invrG, int b0) {
  __shared__ float maskCf[LSEQ];
  __shared__ float lt[64 * 65];
  __shared__ float Ms[64];
  __shared__ float s_ninact;
  const int bz = blockIdx.y;
  const int b = b0 + bz;
  const int r0 = blockIdx.x * 64;
  const int tid = threadIdx.x;
  const int lane = tid & 63;
  if (tid == 0) s_ninact = 0.f;
  __syncthreads();
  float cnt = 0.f;
  for (int j = tid; j < LSEQ; j += 256) {
    const float m = (float)cmask[(size_t)b * LSEQ + j];
    maskCf[j] = m;
    cnt += 1.f - m;
  }
#pragma unroll
  for (int s = 1; s < 64; s <<= 1) cnt += __shfl_xor(cnt, s);
  if (lane == 0) atomicAdd(&s_ninact, cnt);
  __syncthreads();
  const float ninact = s_ninact;
  if (tid < 64) {
    const float* cp = colpart + (size_t)bz * 8 * LSEQ + r0 + tid;
    float m = cp[0];
#pragma unroll
    for (int blk = 1; blk < 8; ++blk) m = fmaxf(m, cp[(size_t)blk * LSEQ]);
    Ms[tid] = (ninact > 0.5f) ? fmaxf(m, 0.f) : m;
  }
  __syncthreads();
  const float* Sb = Sg + (size_t)bz * LSEQ * LSEQ;
  const int sti = tid >> 2, stj = (tid & 3) * 16;  // staging role
  const int rl = tid >> 2, cs = tid & 3;           // compute role (same split)
  const float M = Ms[rl];
  float psum = 0.f;
  for (int ct = 0; ct < 8; ++ct) {
    __syncthreads();  // prev tile reads done
    const float* src = Sb + (size_t)(ct * 64 + sti) * LSEQ + r0 + stj;
#pragma unroll
    for (int q = 0; q < 4; ++q)
      *(f32x4*)&lt[sti * 65 + stj + q * 4] = *(const f32x4*)(src + q * 4);
    __syncthreads();
    const int cb = ct * 64 + cs * 16;
    u16x8 h0, h1;
#pragma unroll
    for (int q = 0; q < 16; ++q) {
      const float v = lt[(cs * 16 + q) * 65 + rl];
      const float p = maskCf[cb + q] * __expf(fminf(v - M, 0.f));
      psum += p;
      if (q < 8) h0[q] = h2u((_Float16)p);
      else h1[q - 8] = h2u((_Float16)p);
    }
    unsigned short* dst = WrG + ((size_t)bz * LSEQ + r0 + rl) * LSEQ + cb;
    *(u16x8*)dst = h0;
    *(u16x8*)(dst + 8) = h1;
  }
  psum += __shfl_xor(psum, 1);
  psum += __shfl_xor(psum, 2);
  if (cs == 0) {
    const float Z = psum + ((ninact > 0.5f) ? ninact * __expf(-M) : 0.f);
    invrG[(size_t)bz * LSEQ + r0 + rl] = 1.f / (psum + 1e-13f * Z);
  }
}

// ---- PV: out[b][m][d] = (sum_n W[m,n]*Vt[d,n]) * scaleM[m], fp16 MFMA ----
// job0: scaleM = cmask; job1: scaleM = rmask * invr (Wr is unnormalized).
// 1-D grid 48*nb, XCD-chunked; 128x128 tile, BK=32, double-buffered LDS.
__global__ __launch_bounds__(256) void k_pv(
    const unsigned short* __restrict__ WcG, const unsigned short* __restrict__ WrG,
    const unsigned short* __restrict__ RT, const unsigned short* __restrict__ CT,
    const int* __restrict__ cmask, const int* __restrict__ rmask,
    const float* __restrict__ invrG, float* __restrict__ out, int b0, int nb) {
  __shared__ __align__(16) unsigned short Alds[2][128 * 32];
  __shared__ __align__(16) unsigned short Blds[2][128 * 32];
  __shared__ float maskMf[128];
  const int nid = xcd_swz(blockIdx.x, 48 * nb);
  const int bz = nid / 48;
  const int rem = nid % 48;
  const int m0 = (rem & 3) * 128;
  int y = rem >> 2;
  const int job = (y >= 6) ? 1 : 0;
  if (job) y -= 6;
  const unsigned short* Wg = job ? WrG : WcG;
  const unsigned short* Vt = job ? CT : RT;
  const int* maskM = job ? rmask : cmask;
  float* outp = out + (job ? (size_t)BATCH * LSEQ * DMODEL : 0);
  const int d0 = y * 128;
  const int tid = threadIdx.x;
  const int lane = tid & 63;
  const int w = tid >> 6;
  const int wm = (w & 1) * 64, wd = (w >> 1) * 64;
  const int l15 = lane & 15, kg = lane >> 4;
  if (tid < 128) {
    float m = (float)maskM[(size_t)(b0 + bz) * LSEQ + m0 + tid];
    if (job) m *= invrG[(size_t)bz * LSEQ + m0 + tid];
    maskMf[tid] = m;
  }
  const unsigned short* Wb = Wg + ((size_t)bz * LSEQ + m0) * LSEQ;
  const unsigned short* Vb = Vt + ((size_t)bz * DMODEL + d0) * LSEQ;
  const int sr = tid >> 2, gp = tid & 3;
  const int gs0 = (gp ^ ((sr >> 1) & 3)) * 8;
  const int gs1 = (gp ^ (((sr + 64) >> 1) & 3)) * 8;

#define PV_STAGE(buf, k0)                                             \
  do {                                                                \
    gload16(Wb + (size_t)sr * LSEQ + (k0) + gs0, &Alds[buf][tid * 8]);\
    gload16(Vb + (size_t)sr * LSEQ + (k0) + gs0, &Blds[buf][tid * 8]);\
    gload16(Wb + (size_t)(sr + 64) * LSEQ + (k0) + gs1,               \
            &Alds[buf][(256 + tid) * 8]);                             \
    gload16(Vb + (size_t)(sr + 64) * LSEQ + (k0) + gs1,               \
            &Blds[buf][(256 + tid) * 8]);                             \
  } while (0)

  f32x4 acc[4][4] = {};
  PV_STAGE(0, 0);
  __syncthreads();
  int cur = 0;
  for (int t = 0; t < 16; ++t) {
    if (t < 15) PV_STAGE(cur ^ 1, (t + 1) * 32);
    f16x8 a[4], bb[4];
#pragma unroll
    for (int f = 0; f < 4; ++f) {
      a[f] = *(const f16x8*)((const char*)Alds[cur] + swz(wm + f * 16 + l15, kg));
      bb[f] = *(const f16x8*)((const char*)Blds[cur] + swz(wd + f * 16 + l15, kg));
    }
#pragma unroll
    for (int fm = 0; fm < 4; ++fm)
#pragma unroll
      for (int fd = 0; fd < 4; ++fd)
        acc[fm][fd] = mfma16(a[fm], bb[fd], acc[fm][fd]);
    __syncthreads();
    cur ^= 1;
  }
#undef PV_STAGE
  const int g4 = (lane >> 4) * 4;
#pragma unroll
  for (int fm = 0; fm < 4; ++fm)
#pragma unroll
    for (int fd = 0; fd < 4; ++fd)
#pragma unroll
      for (int reg = 0; reg < 4; ++reg) {
        const int row = wm + fm * 16 + g4 + reg;
        const int col = wd + fd * 16 + l15;
        outp[((size_t)(b0 + bz) * LSEQ + m0 + row) * DMODEL + d0 + col] =
            acc[fm][fd][reg] * maskMf[row];
      }
}

extern "C" void kernel_launch(void* const* d_in, const int* in_sizes, int n_in,
                              void* d_out, int out_size, void* d_ws, size_t ws_size,
                              hipStream_t stream) {
  const float* context = (const float*)d_in[0];
  const float* response = (const float*)d_in[1];
  const int* cmask = (const int*)d_in[2];
  const int* rmask = (const int*)d_in[3];
  float* out = (float*)d_out;

  const size_t szS1 = (size_t)LSEQ * LSEQ * 4;
  const size_t szT1 = (size_t)LSEQ * DMODEL * 2;
  const size_t szW1 = (size_t)LSEQ * LSEQ * 2;
  const size_t szP1 = (size_t)8 * LSEQ * 4;
  const size_t szI1 = (size_t)LSEQ * 4;
  const size_t perBatch = szS1 + 2 * szT1 + 2 * szW1 + szP1 + szI1;
  int nbc = (int)(ws_size / perBatch);
  if (nbc > BATCH) nbc = BATCH;
  if (nbc < 1) nbc = 1;

  char* base = (char*)d_ws;
  const size_t szS = (size_t)nbc * szS1;
  const size_t szT = (size_t)nbc * szT1;
  const size_t szW = (size_t)nbc * szW1;
  const size_t szP = (size_t)nbc * szP1;
  float* S = (float*)base;
  unsigned short* RT = (unsigned short*)(base + szS);
  unsigned short* CT = (unsigned short*)(base + szS + szT);
  unsigned short* Wc = (unsigned short*)(base + szS + 2 * szT);
  unsigned short* Wr = (unsigned short*)(base + szS + 2 * szT + szW);
  float* colpart = (float*)(base + szS + 2 * szT + 2 * szW);
  float* invr = (float*)(base + szS + 2 * szT + 2 * szW + szP);

  for (int b0 = 0; b0 < BATCH; b0 += nbc) {
    int nb = BATCH - b0;
    if (nb > nbc) nb = nbc;
    dim3 blk(256);
    k_main<<<dim3(208 * nb), blk, 0, stream>>>(context, response, S, RT, CT, b0, nb);
    k_sm1<<<dim3(8, nb), blk, 0, stream>>>(S, rmask, cmask, Wc, colpart, b0);
    k_sm2<<<dim3(8, nb), blk, 0, stream>>>(S, cmask, colpart, Wr, invr, b0);
    k_pv<<<dim3(48 * nb), blk, 0, stream>>>(Wc, Wr, RT, CT, cmask, rmask, invr, out, b0, nb);
  }
}